// Round 16
// baseline (522.045 us; speedup 1.0000x reference)
//
#include <hip/hip_runtime.h>
#include <hip/hip_bf16.h>
#include <math.h>

#define N_NODES 100000
#define N_EDGES 1600000
#define N_FEAT 64
#define HID 64
#define HL 256
#define N_GRAPHS 512

#define BUCKET_BITS 7
#define BUCKET_SIZE 128
#define NB ((N_NODES + BUCKET_SIZE - 1) / BUCKET_SIZE)   // 782
#define LOFS_W (NB + 1)                                  // 783
#define CAP 4608                   // per-bucket soff capacity incl. 16-pads
#define LREC_CAP 3584              // staged records per bucket (max ~2300)
#define EDGES_PER_BLOCK 4096
#define SCAT_BLOCKS ((N_EDGES + EDGES_PER_BLOCK - 1) / EDGES_PER_BLOCK)  // 391
#define F2B_BLOCKS (N_NODES * 16 / 256)                                  // 6250
#define WPREP_BLOCKS 128

// 4 feature planes: plane p = features [16p, 16p+16), 32 B per node.
// Per-XCD gather working set = one 3.2 MB plane -> L2-resident under the
// round-robin blockIdx->XCD heuristic (r8 measured FETCH 80->33 MB).
#define PSTR 3200256u              // h plane stride, bytes (N*32 + zero row + pad)
#define PSTRU (PSTR / 2)
#define ASTR 3200000u              // aggb plane stride, bytes (N*32)
#define ASTRU (ASTR / 2)
#define ZOFF32 ((unsigned)N_NODES * 32u)   // zero-row byte offset within a plane

typedef short vbf8 __attribute__((ext_vector_type(8)));
typedef float vf4 __attribute__((ext_vector_type(4)));
typedef float vf2 __attribute__((ext_vector_type(2)));

__device__ __forceinline__ unsigned short f2b(float f) {
    unsigned int u = __float_as_uint(f);
    return (unsigned short)((u + 0x7FFFu + ((u >> 16) & 1u)) >> 16);
}
__device__ __forceinline__ float b2f(unsigned short u) {
    return __uint_as_float(((unsigned int)u) << 16);
}
__device__ __forceinline__ unsigned pk2(float lo, float hi) {
    float2 f; f.x = lo; f.y = hi;
    __hip_bfloat162 h = __float22bfloat162_rn(f);
    unsigned r;
    __builtin_memcpy(&r, &h, 4);
    return r;
}
__device__ __forceinline__ vf2 bpair(unsigned int d) {
    vf2 r;
    r.x = __uint_as_float(d << 16);
    r.y = __uint_as_float(d & 0xFFFF0000u);
    return r;
}

// ---------------- mega prep: LDS bucket-sort + f2b + wprep -----------------

__global__ __launch_bounds__(256) void k_mega(
        const int* __restrict__ src, const int* __restrict__ dst,
        int* __restrict__ lofs, unsigned int* __restrict__ ebuf,
        const float4* __restrict__ x, unsigned short* __restrict__ xb,
        const float* __restrict__ wroot0, const float* __restrict__ wrel0,
        const float* __restrict__ wroot1, const float* __restrict__ wrel1,
        const float* __restrict__ wroot2, const float* __restrict__ wrel2,
        const float* __restrict__ wroot3, const float* __restrict__ wrel3,
        unsigned short* __restrict__ wt) {
    __shared__ int lh[NB];
    __shared__ int lsc[256];
    __shared__ unsigned lrec[EDGES_PER_BLOCK];
    int bid = blockIdx.x;
    int t = threadIdx.x;

    if (bid < SCAT_BLOCKS) {
        for (int i = t; i < NB; i += 256) lh[i] = 0;
        __syncthreads();
        int i0 = bid * EDGES_PER_BLOCK;
        int i1 = min(N_EDGES, i0 + EDGES_PER_BLOCK);
        int cnt = i1 - i0;
        for (int i = i0 + t; i < i1; i += 256)
            atomicAdd(&lh[dst[i] >> BUCKET_BITS], 1);
        __syncthreads();
        int v[4];
        int s = 0;
        int base4 = t * 4;
#pragma unroll
        for (int j = 0; j < 4; j++) {
            v[j] = (base4 + j < NB) ? lh[base4 + j] : 0;
            s += v[j];
        }
        lsc[t] = s;
        __syncthreads();
        for (int off = 1; off < 256; off <<= 1) {
            int xx = lsc[t];
            int y = (t >= off) ? lsc[t - off] : 0;
            __syncthreads();
            lsc[t] = xx + y;
            __syncthreads();
        }
        int run = lsc[t] - s;
        int* lrow = lofs + (size_t)bid * LOFS_W;
#pragma unroll
        for (int j = 0; j < 4; j++) {
            int b = base4 + j;
            if (b < NB) {
                lrow[b] = run;
                lh[b] = run;
            }
            run += v[j];
        }
        if (t == 255) lrow[NB] = cnt;
        __syncthreads();
        for (int i = i0 + t; i < i1; i += 256) {
            int sN = src[i], d = dst[i];
            int b = d >> BUCKET_BITS;
            int p = atomicAdd(&lh[b], 1);
            lrec[p] = ((unsigned)sN << 7) | (unsigned)(d & 127);
        }
        __syncthreads();
        unsigned* eb = ebuf + (size_t)bid * EDGES_PER_BLOCK;
        for (int j = t; j < cnt; j += 256) eb[j] = lrec[j];
    } else if (bid < SCAT_BLOCKS + F2B_BLOCKS) {
        // ---- fp32 -> bf16 convert into plane layout ----
        int i = (bid - SCAT_BLOCKS) * 256 + t;
        if (i < N_NODES * 16) {
            float4 v = x[i];
            int node = i >> 4, kc = i & 15;   // kc = feature quad
            uint2 o;
            o.x = pk2(v.x, v.y);
            o.y = pk2(v.z, v.w);
            *(uint2*)((char*)xb + (size_t)(kc >> 2) * PSTR +
                      (size_t)node * 32 + (kc & 3) * 8) = o;
        }
    } else {
        // ---- weight prep: Wt[layer][n][k], k = [wroot|wrel] ----
        int gi = (bid - SCAT_BLOCKS - F2B_BLOCKS) * 256 + t;
        if (gi < 4 * 64 * 128) {
            int layer = gi >> 13;
            int i = gi & 8191;
            int nn = i >> 7, k = i & 127;
            const float* wr = (layer == 0) ? wroot0 : (layer == 1) ? wroot1
                             : (layer == 2) ? wroot2 : wroot3;
            const float* wl = (layer == 0) ? wrel0 : (layer == 1) ? wrel1
                             : (layer == 2) ? wrel2 : wrel3;
            float v = (k < 64) ? wr[k * 64 + nn] : wl[(k - 64) * 64 + nn];
            wt[gi] = f2b(v);
        }
    }
}

// ---------------- per-bucket: gather runs -> hist -> 16-padded scan -> soff
// soff stores plane byte offsets (src*32); per-node lists padded to a
// multiple of 16 with ZOFF32 (zero-row) entries -> no tail logic in agg.

__global__ __launch_bounds__(256) void k_fscatter2(
        const unsigned int* __restrict__ ebuf, const int* __restrict__ lofs,
        int2* __restrict__ re, unsigned int* __restrict__ soff,
        unsigned short* __restrict__ hbA, unsigned short* __restrict__ hbB, int n) {
    __shared__ int rcnt[512];
    __shared__ int rbase[512];
    __shared__ int rpre[512];
    __shared__ int tsc[256];
    __shared__ unsigned lrec[LREC_CAP];
    __shared__ int lcnt[BUCKET_SIZE];
    __shared__ int sc[BUCKET_SIZE];
    __shared__ int cur[BUCKET_SIZE];
    int b = blockIdx.x;
    int n0 = b * BUCKET_SIZE;
    int t = threadIdx.x;
    if (b == 0 && t < 8) {
        // zero the 32B zero row of each of 4 planes, both h buffers
        int plane = t & 3;
        unsigned short* hp = (t < 4) ? hbA : hbB;
        uint4 z = make_uint4(0u, 0u, 0u, 0u);
        uint4* zp = (uint4*)((char*)hp + (size_t)plane * PSTR + (size_t)N_NODES * 32);
        zp[0] = z;
        zp[1] = z;
    }
    for (int blk = t; blk < 512; blk += 256) {
        int c = 0, ba = 0;
        if (blk < SCAT_BLOCKS) {
            const int* lr = lofs + (size_t)blk * LOFS_W + b;
            ba = lr[0];
            c = lr[1] - ba;
        }
        rcnt[blk] = c;
        rbase[blk] = ba;
    }
    __syncthreads();
    int c0 = rcnt[2 * t], c1 = rcnt[2 * t + 1];
    tsc[t] = c0 + c1;
    __syncthreads();
    for (int off = 1; off < 256; off <<= 1) {
        int xx = tsc[t];
        int y = (t >= off) ? tsc[t - off] : 0;
        __syncthreads();
        tsc[t] = xx + y;
        __syncthreads();
    }
    int ex = tsc[t] - (c0 + c1);
    rpre[2 * t] = ex;
    rpre[2 * t + 1] = ex + c0;
    __syncthreads();
    int cb = tsc[255];
    for (int blk = t; blk < SCAT_BLOCKS; blk += 256) {
        int c = rcnt[blk];
        int dsto = rpre[blk];
        const unsigned* sp = ebuf + (size_t)blk * EDGES_PER_BLOCK + rbase[blk];
        for (int j = 0; j < c; j++) lrec[dsto + j] = sp[j];
    }
    if (t < BUCKET_SIZE) lcnt[t] = 0;
    __syncthreads();
    for (int r = t; r < cb; r += 256)
        atomicAdd(&lcnt[lrec[r] & 127u], 1);
    __syncthreads();
    int v = 0, pcnt = 0;
    if (t < BUCKET_SIZE) {
        v = lcnt[t];
        pcnt = (v + 15) & ~15;   // pad to multiple of 16
        sc[t] = pcnt;
    }
    __syncthreads();
    for (int off = 1; off < BUCKET_SIZE; off <<= 1) {
        int xx = 0;
        if (t < BUCKET_SIZE) {
            xx = sc[t];
            if (t >= off) xx += sc[t - off];
        }
        __syncthreads();
        if (t < BUCKET_SIZE) sc[t] = xx;
        __syncthreads();
    }
    if (t < BUCKET_SIZE) {
        int start = b * CAP + sc[t] - pcnt;
        if (n0 + t < n) re[n0 + t] = make_int2(start, start + v);
        cur[t] = start;
        for (int z = start + v; z < start + pcnt; z++) soff[z] = ZOFF32;
    }
    __syncthreads();
    for (int r = t; r < cb; r += 256) {
        unsigned rec = lrec[r];
        int p = atomicAdd(&cur[rec & 127u], 1);
        soff[p] = (rec >> 7) * 32u;   // src * 32 = plane byte offset
    }
}

// ---------------- aggregation (XCD-sliced planes, 4 nodes/wave) ------------
// Block b: slice s = b&3 (round-robin -> each XCD gathers one L2-resident
// 3.2 MB plane). Wave = 4 nodes; per node one VMEM instr covers 16 edges
// (lane = q*4+sl: q = edge 0..15, sl = 8B piece 0..3 of the 32B slice).
// 4 independent gather chains/wave; wave count unchanged vs row-major (100k).

__global__ __launch_bounds__(256) void k_agg(
    const unsigned short* __restrict__ hb, unsigned short* __restrict__ aggb,
    const int2* __restrict__ re, const unsigned int* __restrict__ soff, int n) {
    int l = threadIdx.x & 63;
    int w = threadIdx.x >> 6;
    int s = blockIdx.x & 3;
    int i0 = (blockIdx.x >> 2) * 16 + w * 4;
    if (i0 >= n) return;
    int q = l >> 2, sl = l & 3;
    const char* base = (const char*)hb + (size_t)s * PSTR + sl * 8;

    int2 b0 = re[i0];
    int2 b1 = re[min(i0 + 1, n - 1)];
    int2 b2 = re[min(i0 + 2, n - 1)];
    int2 b3 = re[min(i0 + 3, n - 1)];
    int it0 = (b0.y - b0.x + 15) >> 4;
    int it1 = (i0 + 1 < n) ? (b1.y - b1.x + 15) >> 4 : 0;
    int it2 = (i0 + 2 < n) ? (b2.y - b2.x + 15) >> 4 : 0;
    int it3 = (i0 + 3 < n) ? (b3.y - b3.x + 15) >> 4 : 0;
    int iters = max(max(it0, it1), max(it2, it3));

    vf2 acc[4][2];
#pragma unroll
    for (int j = 0; j < 4; j++) {
        acc[j][0] = (vf2){0.f, 0.f};
        acc[j][1] = (vf2){0.f, 0.f};
    }

    for (int it = 0; it < iters; it++) {
        int step = it * 16 + q;
        unsigned o0 = soff[(it < it0) ? (b0.x + step) : 0];
        unsigned o1 = soff[(it < it1) ? (b1.x + step) : 0];
        unsigned o2 = soff[(it < it2) ? (b2.x + step) : 0];
        unsigned o3 = soff[(it < it3) ? (b3.x + step) : 0];
        if (it >= it0) o0 = ZOFF32;
        if (it >= it1) o1 = ZOFF32;
        if (it >= it2) o2 = ZOFF32;
        if (it >= it3) o3 = ZOFF32;
        uint2 d0 = *(const uint2*)(base + o0);
        uint2 d1 = *(const uint2*)(base + o1);
        uint2 d2 = *(const uint2*)(base + o2);
        uint2 d3 = *(const uint2*)(base + o3);
        acc[0][0] += bpair(d0.x); acc[0][1] += bpair(d0.y);
        acc[1][0] += bpair(d1.x); acc[1][1] += bpair(d1.y);
        acc[2][0] += bpair(d2.x); acc[2][1] += bpair(d2.y);
        acc[3][0] += bpair(d3.x); acc[3][1] += bpair(d3.y);
    }

    // fold edge dim (lane bits 2..5); then lanes q==0 hold totals
    float f[4][4];
#pragma unroll
    for (int j = 0; j < 4; j++) {
        float a0 = acc[j][0].x, a1 = acc[j][0].y;
        float a2 = acc[j][1].x, a3 = acc[j][1].y;
        a0 += __shfl_xor(a0, 4);  a0 += __shfl_xor(a0, 8);
        a0 += __shfl_xor(a0, 16); a0 += __shfl_xor(a0, 32);
        a1 += __shfl_xor(a1, 4);  a1 += __shfl_xor(a1, 8);
        a1 += __shfl_xor(a1, 16); a1 += __shfl_xor(a1, 32);
        a2 += __shfl_xor(a2, 4);  a2 += __shfl_xor(a2, 8);
        a2 += __shfl_xor(a2, 16); a2 += __shfl_xor(a2, 32);
        a3 += __shfl_xor(a3, 4);  a3 += __shfl_xor(a3, 8);
        a3 += __shfl_xor(a3, 16); a3 += __shfl_xor(a3, 32);
        f[j][0] = a0; f[j][1] = a1; f[j][2] = a2; f[j][3] = a3;
    }
    if (q == 0) {
        char* ab = (char*)aggb + (size_t)s * ASTR + sl * 8;
#pragma unroll
        for (int j = 0; j < 4; j++) {
            if (i0 + j < n) {
                uint2 o;
                o.x = pk2(f[j][0], f[j][1]);
                o.y = pk2(f[j][2], f[j][3]);
                *(uint2*)(ab + (size_t)(i0 + j) * 32) = o;
            }
        }
    }
}

// ---------------- MFMA gemm: plane-layout inputs/outputs -------------------

template <int RELU>
__global__ __launch_bounds__(256) void k_gemm(
    const unsigned short* __restrict__ hb, const unsigned short* __restrict__ aggb,
    const unsigned short* __restrict__ wt, const float* __restrict__ brel,
    unsigned short* __restrict__ hbout, int n) {
    __shared__ float sc[4][16 * 68];

    int tid = threadIdx.x;
    int w = tid >> 6, l = tid & 63;
    int lm = l & 15, q = l >> 4;
    int r0 = blockIdx.x * 64 + w * 16;

    int arow = r0 + lm;
    if (arow >= n) arow = n - 1;
    size_t rowoff = (size_t)arow * 16;   // ushorts per plane row
    int p0 = q >> 1;
    int half = (q & 1) * 8;
    vbf8 afr[4];
    afr[0] = *(const vbf8*)(hb + (size_t)p0 * PSTRU + rowoff + half);
    afr[1] = *(const vbf8*)(hb + (size_t)(p0 + 2) * PSTRU + rowoff + half);
    afr[2] = *(const vbf8*)(aggb + (size_t)p0 * ASTRU + rowoff + half);
    afr[3] = *(const vbf8*)(aggb + (size_t)(p0 + 2) * ASTRU + rowoff + half);

    vf4 acc[4];
#pragma unroll
    for (int t = 0; t < 4; t++) acc[t] = (vf4){0.f, 0.f, 0.f, 0.f};

#pragma unroll
    for (int t = 0; t < 4; t++) {
        const unsigned short* wrow = wt + (size_t)(t * 16 + lm) * 128 + q * 8;
#pragma unroll
        for (int s = 0; s < 4; s++) {
            vbf8 bfr = *(const vbf8*)(wrow + s * 32);
            acc[t] = __builtin_amdgcn_mfma_f32_16x16x32_bf16(afr[s], bfr, acc[t], 0, 0, 0);
        }
    }

    float* sw_ = sc[w];
#pragma unroll
    for (int t = 0; t < 4; t++) {
        float b = brel[t * 16 + lm];
#pragma unroll
        for (int i = 0; i < 4; i++) {
            float v = acc[t][i] + b;
            if (RELU) v = fmaxf(v, 0.f);
            sw_[(q * 4 + i) * 68 + t * 16 + lm] = v;
        }
    }
    int rr = l >> 2, cs = l & 3;
    int node = r0 + rr;
    if (node < n) {
        const float* rp = sw_ + rr * 68 + cs * 16;
        float4 v0 = *(const float4*)(rp);
        float4 v1 = *(const float4*)(rp + 4);
        float4 v2 = *(const float4*)(rp + 8);
        float4 v3 = *(const float4*)(rp + 12);
        uint4 o0, o1;
        o0.x = pk2(v0.x, v0.y);
        o0.y = pk2(v0.z, v0.w);
        o0.z = pk2(v1.x, v1.y);
        o0.w = pk2(v1.z, v1.w);
        o1.x = pk2(v2.x, v2.y);
        o1.y = pk2(v2.z, v2.w);
        o1.z = pk2(v3.x, v3.y);
        o1.w = pk2(v3.z, v3.w);
        // features [cs*16, cs*16+16) == plane cs, 32B row
        char* outb = (char*)hbout + (size_t)cs * PSTR + (size_t)node * 32;
        *(uint4*)outb = o0;
        *(uint4*)(outb + 16) = o1;
    }
}

// ---------------- fused pool + MLP head (plane-layout reads) ---------------

__global__ __launch_bounds__(256) void k_poolmlp(
    const unsigned short* __restrict__ hb, const int* __restrict__ batch,
    const float* __restrict__ T, const float* __restrict__ w1,
    const float* __restrict__ b1, const float* __restrict__ w2,
    const float* __restrict__ b2, const float* __restrict__ w3,
    const float* __restrict__ b3, float* __restrict__ out, int n) {
    __shared__ float psum[4][64];
    __shared__ float pmax[4][64];
    __shared__ float sin_[200];
    __shared__ float so1[256];
    __shared__ float red[256];
    int g = blockIdx.x, t = threadIdx.x;
    int l = t & 63, c = t >> 6;

    int lo = 0, hi = n;
    while (lo < hi) { int m = (lo + hi) >> 1; if (batch[m] < g) lo = m + 1; else hi = m; }
    int s0 = lo;
    int lo2 = s0, hi2 = n;
    while (lo2 < hi2) { int m = (lo2 + hi2) >> 1; if (batch[m] < g + 1) lo2 = m + 1; else hi2 = m; }
    int s1 = lo2;

    // feature l -> plane l>>4, ushort (l&15) within the 16-ushort row
    size_t fb = (size_t)(l >> 4) * PSTRU + (size_t)(l & 15);
    float sa0 = 0.f, sa1 = 0.f, sa2 = 0.f, sa3 = 0.f;
    float ma0 = -INFINITY, ma1 = -INFINITY, ma2 = -INFINITY, ma3 = -INFINITY;
    int nn = s0 + c;
    for (; nn + 12 < s1; nn += 16) {
        float v0 = b2f(hb[fb + (size_t)nn * 16]);
        float v1 = b2f(hb[fb + (size_t)(nn + 4) * 16]);
        float v2 = b2f(hb[fb + (size_t)(nn + 8) * 16]);
        float v3 = b2f(hb[fb + (size_t)(nn + 12) * 16]);
        sa0 += v0; sa1 += v1; sa2 += v2; sa3 += v3;
        ma0 = fmaxf(ma0, v0); ma1 = fmaxf(ma1, v1);
        ma2 = fmaxf(ma2, v2); ma3 = fmaxf(ma3, v3);
    }
    for (; nn < s1; nn += 4) {
        float v = b2f(hb[fb + (size_t)nn * 16]);
        sa0 += v;
        ma0 = fmaxf(ma0, v);
    }
    psum[c][l] = (sa0 + sa1) + (sa2 + sa3);
    pmax[c][l] = fmaxf(fmaxf(ma0, ma1), fmaxf(ma2, ma3));
    __syncthreads();
    if (t < 64) {
        float s = (psum[0][t] + psum[1][t]) + (psum[2][t] + psum[3][t]);
        float mx = fmaxf(fmaxf(pmax[0][t], pmax[1][t]), fmaxf(pmax[2][t], pmax[3][t]));
        int cnt = s1 - s0;
        float mean = s / fmaxf((float)cnt, 1.f);
        if (cnt == 0) mx = 0.f;
        sin_[t] = mx;
        sin_[64 + t] = mean;
        sin_[128 + t] = s;
        if (t == 0) {
            sin_[192] = T[g];
#pragma unroll
            for (int z = 193; z < 200; z++) sin_[z] = 0.f;
        }
    }
    __syncthreads();

    float a = b1[t];
    {
        float wv[8];
        for (int k = 0; k < 192; k += 8) {
#pragma unroll
            for (int u = 0; u < 8; u++) wv[u] = w1[(k + u) * 256 + t];
#pragma unroll
            for (int u = 0; u < 8; u++) a += sin_[k + u] * wv[u];
        }
        a += sin_[192] * w1[192 * 256 + t];
    }
    a = fmaxf(a, 0.f);
    so1[t] = a;
    __syncthreads();

    float a2 = b2[t];
    {
        float wv[8];
        for (int k = 0; k < 256; k += 8) {
#pragma unroll
            for (int u = 0; u < 8; u++) wv[u] = w2[(k + u) * 256 + t];
#pragma unroll
            for (int u = 0; u < 8; u++) a2 += so1[k + u] * wv[u];
        }
    }
    a2 = fmaxf(a2, 0.f);
    red[t] = a2 * w3[t];
    __syncthreads();
    for (int s = 128; s > 0; s >>= 1) {
        if (t < s) red[t] += red[t + s];
        __syncthreads();
    }
    if (t == 0) out[g] = red[0] + b3[0];
}

extern "C" void kernel_launch(void* const* d_in, const int* in_sizes, int n_in,
                              void* d_out, int out_size, void* d_ws, size_t ws_size,
                              hipStream_t stream) {
    const int N = N_NODES, E = N_EDGES, G = N_GRAPHS;

    const float* x = (const float*)d_in[0];
    const int* ei = (const int*)d_in[1];
    const int* batch = (const int*)d_in[2];
    const float* T = (const float*)d_in[3];
    const float* wrel[4] = {(const float*)d_in[4], (const float*)d_in[7],
                            (const float*)d_in[10], (const float*)d_in[13]};
    const float* brel[4] = {(const float*)d_in[5], (const float*)d_in[8],
                            (const float*)d_in[11], (const float*)d_in[14]};
    const float* wroot[4] = {(const float*)d_in[6], (const float*)d_in[9],
                             (const float*)d_in[12], (const float*)d_in[15]};
    const float* w1 = (const float*)d_in[16];
    const float* b1 = (const float*)d_in[17];
    const float* w2 = (const float*)d_in[18];
    const float* b2 = (const float*)d_in[19];
    const float* w3 = (const float*)d_in[20];
    const float* b3 = (const float*)d_in[21];
    float* out = (float*)d_out;

    const int* esrc = ei;
    const int* edst = ei + E;

    // workspace layout (~66 MB)
    char* ws = (char*)d_ws;
    size_t off = 0;
    auto alloc = [&](size_t bytes) {
        size_t r = off;
        off = (off + bytes + 255) & ~(size_t)255;
        return r;
    };
    int* lofs = (int*)(ws + alloc((size_t)SCAT_BLOCKS * LOFS_W * 4));
    int2* re = (int2*)(ws + alloc((size_t)N * 8));
    unsigned int* soff = (unsigned int*)(ws + alloc((size_t)NB * CAP * 4 + 8192));
    unsigned int* ebuf = (unsigned int*)(ws + alloc((size_t)SCAT_BLOCKS * EDGES_PER_BLOCK * 4));
    unsigned short* hbA = (unsigned short*)(ws + alloc((size_t)4 * PSTR));
    unsigned short* hbB = (unsigned short*)(ws + alloc((size_t)4 * PSTR));
    unsigned short* aggb = (unsigned short*)(ws + alloc((size_t)4 * ASTR));
    unsigned short* wt = (unsigned short*)(ws + alloc((size_t)4 * 64 * 128 * 2));

    // 1. prep: mega (LDS bucket-sort scatter + f2b + wprep), then fscatter2
    k_mega<<<SCAT_BLOCKS + F2B_BLOCKS + WPREP_BLOCKS, 256, 0, stream>>>(
        esrc, edst, lofs, ebuf, (const float4*)x, hbA,
        wroot[0], wrel[0], wroot[1], wrel[1],
        wroot[2], wrel[2], wroot[3], wrel[3], wt);
    k_fscatter2<<<NB, 256, 0, stream>>>(ebuf, lofs, re, soff, hbA, hbB, N);

    // 2. four conv layers (bf16 plane ping-pong, MFMA gemm)
    int agg_blocks = ((N + 15) / 16) * 4;    // 16 nodes x 4 slices per block
    int gemm_blocks = (N + 63) / 64;         // 64-node tile per block

    k_agg<<<agg_blocks, 256, 0, stream>>>(hbA, aggb, re, soff, N);
    k_gemm<1><<<gemm_blocks, 256, 0, stream>>>(hbA, aggb, wt + 0 * 8192, brel[0], hbB, N);

    k_agg<<<agg_blocks, 256, 0, stream>>>(hbB, aggb, re, soff, N);
    k_gemm<1><<<gemm_blocks, 256, 0, stream>>>(hbB, aggb, wt + 1 * 8192, brel[1], hbA, N);

    k_agg<<<agg_blocks, 256, 0, stream>>>(hbA, aggb, re, soff, N);
    k_gemm<1><<<gemm_blocks, 256, 0, stream>>>(hbA, aggb, wt + 2 * 8192, brel[2], hbB, N);

    k_agg<<<agg_blocks, 256, 0, stream>>>(hbB, aggb, re, soff, N);
    k_gemm<0><<<gemm_blocks, 256, 0, stream>>>(hbB, aggb, wt + 3 * 8192, brel[3], hbA, N);

    // 3. fused pooling + MLP head
    k_poolmlp<<<G, 256, 0, stream>>>(hbA, batch, T, w1, b1, w2, b2, w3, b3, out, N);
}

// Round 17
// 400.694 us; speedup vs baseline: 1.3029x; 1.3029x over previous
//
#include <hip/hip_runtime.h>
#include <hip/hip_bf16.h>
#include <math.h>

#define N_NODES 100000
#define N_EDGES 1600000
#define N_FEAT 64
#define HID 64
#define HL 256
#define N_GRAPHS 512

#define BUCKET_BITS 7
#define BUCKET_SIZE 128
#define NB ((N_NODES + BUCKET_SIZE - 1) / BUCKET_SIZE)   // 782
#define LOFS_W (NB + 1)                                  // 783
#define CAP 3584                   // per-bucket soff capacity incl. 8-pads
#define LREC_CAP 3584              // staged records per bucket (max ~2300)
#define EDGES_PER_BLOCK 4096
#define SCAT_BLOCKS ((N_EDGES + EDGES_PER_BLOCK - 1) / EDGES_PER_BLOCK)  // 391
#define F2B_BLOCKS (N_NODES * 16 / 256)                                  // 6250
#define WPREP_BLOCKS 128
#define ZOFF ((unsigned int)N_NODES * 128u)   // byte offset of the zero row

typedef short vbf8 __attribute__((ext_vector_type(8)));
typedef float vf4 __attribute__((ext_vector_type(4)));
typedef float vf2 __attribute__((ext_vector_type(2)));

// bf16 helpers (manual RNE; values are finite)
__device__ __forceinline__ unsigned short f2b(float f) {
    unsigned int u = __float_as_uint(f);
    return (unsigned short)((u + 0x7FFFu + ((u >> 16) & 1u)) >> 16);
}
__device__ __forceinline__ float b2f(unsigned short u) {
    return __uint_as_float(((unsigned int)u) << 16);
}
// packed fp32x2 -> bf16x2 (v_cvt_pk_bf16_f32, RNE — identical to f2b)
__device__ __forceinline__ unsigned pk2(float lo, float hi) {
    float2 f; f.x = lo; f.y = hi;
    __hip_bfloat162 h = __float22bfloat162_rn(f);
    unsigned r;
    __builtin_memcpy(&r, &h, 4);
    return r;
}
// bf16 pair -> float2 {lo, hi} (shift + and; pairs with v_pk_add_f32)
__device__ __forceinline__ vf2 bpair(unsigned int d) {
    vf2 r;
    r.x = __uint_as_float(d << 16);
    r.y = __uint_as_float(d & 0xFFFF0000u);
    return r;
}

// ---------------- mega prep: LDS bucket-sort + f2b + wprep -----------------
// Scatter branch: block bucket-sorts its 4096 records in LDS, streams out one
// coalesced contiguous run (ebuf write amp = 1), writes its lofs row.
// NO global atomics anywhere.

__global__ __launch_bounds__(256) void k_mega(
        const int* __restrict__ src, const int* __restrict__ dst,
        int* __restrict__ lofs, unsigned int* __restrict__ ebuf,
        const float4* __restrict__ x, uint2* __restrict__ xb,
        const float* __restrict__ wroot0, const float* __restrict__ wrel0,
        const float* __restrict__ wroot1, const float* __restrict__ wrel1,
        const float* __restrict__ wroot2, const float* __restrict__ wrel2,
        const float* __restrict__ wroot3, const float* __restrict__ wrel3,
        unsigned short* __restrict__ wt) {
    __shared__ int lh[NB];
    __shared__ int lsc[256];
    __shared__ unsigned lrec[EDGES_PER_BLOCK];
    int bid = blockIdx.x;
    int t = threadIdx.x;

    if (bid < SCAT_BLOCKS) {
        for (int i = t; i < NB; i += 256) lh[i] = 0;
        __syncthreads();
        int i0 = bid * EDGES_PER_BLOCK;
        int i1 = min(N_EDGES, i0 + EDGES_PER_BLOCK);
        int cnt = i1 - i0;
        for (int i = i0 + t; i < i1; i += 256)
            atomicAdd(&lh[dst[i] >> BUCKET_BITS], 1);
        __syncthreads();
        // exclusive scan of lh[0..NB), 4 entries/thread
        int v[4];
        int s = 0;
        int base4 = t * 4;
#pragma unroll
        for (int j = 0; j < 4; j++) {
            v[j] = (base4 + j < NB) ? lh[base4 + j] : 0;
            s += v[j];
        }
        lsc[t] = s;
        __syncthreads();
        for (int off = 1; off < 256; off <<= 1) {
            int xx = lsc[t];
            int y = (t >= off) ? lsc[t - off] : 0;
            __syncthreads();
            lsc[t] = xx + y;
            __syncthreads();
        }
        int run = lsc[t] - s;   // exclusive prefix
        int* lrow = lofs + (size_t)bid * LOFS_W;
#pragma unroll
        for (int j = 0; j < 4; j++) {
            int b = base4 + j;
            if (b < NB) {
                lrow[b] = run;
                lh[b] = run;   // LDS cursor (all lh reads completed pre-scan)
            }
            run += v[j];
        }
        if (t == 255) lrow[NB] = cnt;
        __syncthreads();
        // scatter into LDS
        for (int i = i0 + t; i < i1; i += 256) {
            int sN = src[i], d = dst[i];
            int b = d >> BUCKET_BITS;
            int p = atomicAdd(&lh[b], 1);
            lrec[p] = ((unsigned)sN << 7) | (unsigned)(d & 127);
        }
        __syncthreads();
        // stream out coalesced
        unsigned* eb = ebuf + (size_t)bid * EDGES_PER_BLOCK;
        for (int j = t; j < cnt; j += 256) eb[j] = lrec[j];
    } else if (bid < SCAT_BLOCKS + F2B_BLOCKS) {
        // ---- fp32 -> bf16 convert (packed cvt) ----
        int i = (bid - SCAT_BLOCKS) * 256 + t;
        if (i < N_NODES * 16) {
            float4 v = x[i];
            uint2 o;
            o.x = pk2(v.x, v.y);
            o.y = pk2(v.z, v.w);
            xb[i] = o;
        }
    } else {
        // ---- weight prep: Wt[layer][n][k], k = [wroot|wrel] ----
        int gi = (bid - SCAT_BLOCKS - F2B_BLOCKS) * 256 + t;
        if (gi < 4 * 64 * 128) {
            int layer = gi >> 13;
            int i = gi & 8191;
            int nn = i >> 7, k = i & 127;
            const float* wr = (layer == 0) ? wroot0 : (layer == 1) ? wroot1
                             : (layer == 2) ? wroot2 : wroot3;
            const float* wl = (layer == 0) ? wrel0 : (layer == 1) ? wrel1
                             : (layer == 2) ? wrel2 : wrel3;
            float v = (k < 64) ? wr[k * 64 + nn] : wl[(k - 64) * 64 + nn];
            wt[gi] = f2b(v);
        }
    }
}

// ---------------- per-bucket: gather runs -> hist -> padded scan -> soff ---
// Phase 0 reconstructs the bucket: scan the 391 per-block run counts
// (lofs[blk][b+1]-lofs[blk][b]) and gather runs into LDS. Then:
// per-node 8-padded edge lists with ZOFF pads (no tail check in agg).

__global__ __launch_bounds__(256) void k_fscatter2(
        const unsigned int* __restrict__ ebuf, const int* __restrict__ lofs,
        int2* __restrict__ re, unsigned int* __restrict__ soff,
        unsigned short* __restrict__ hbA, unsigned short* __restrict__ hbB, int n) {
    __shared__ int rcnt[512];
    __shared__ int rbase[512];
    __shared__ int rpre[512];
    __shared__ int tsc[256];
    __shared__ unsigned lrec[LREC_CAP];
    __shared__ int lcnt[BUCKET_SIZE];
    __shared__ int sc[BUCKET_SIZE];
    __shared__ int cur[BUCKET_SIZE];
    int b = blockIdx.x;
    int n0 = b * BUCKET_SIZE;
    int t = threadIdx.x;
    if (b == 0 && t < 16) {
        // zero the pad rows (128 B each) of both h buffers
        uint4 z = make_uint4(0u, 0u, 0u, 0u);
        unsigned short* hp = (t < 8) ? hbA : hbB;
        ((uint4*)(hp + (size_t)N_NODES * 64))[t & 7] = z;
    }
    // load per-block run counts/bases for this bucket
    for (int blk = t; blk < 512; blk += 256) {
        int c = 0, ba = 0;
        if (blk < SCAT_BLOCKS) {
            const int* lr = lofs + (size_t)blk * LOFS_W + b;
            ba = lr[0];
            c = lr[1] - ba;
        }
        rcnt[blk] = c;
        rbase[blk] = ba;
    }
    __syncthreads();
    // scan 512 run counts (2 per thread)
    int c0 = rcnt[2 * t], c1 = rcnt[2 * t + 1];
    tsc[t] = c0 + c1;
    __syncthreads();
    for (int off = 1; off < 256; off <<= 1) {
        int xx = tsc[t];
        int y = (t >= off) ? tsc[t - off] : 0;
        __syncthreads();
        tsc[t] = xx + y;
        __syncthreads();
    }
    int ex = tsc[t] - (c0 + c1);
    rpre[2 * t] = ex;
    rpre[2 * t + 1] = ex + c0;
    __syncthreads();
    int cb = tsc[255];   // total records in this bucket
    // gather runs into LDS
    for (int blk = t; blk < SCAT_BLOCKS; blk += 256) {
        int c = rcnt[blk];
        int dsto = rpre[blk];
        const unsigned* sp = ebuf + (size_t)blk * EDGES_PER_BLOCK + rbase[blk];
        for (int j = 0; j < c; j++) lrec[dsto + j] = sp[j];
    }
    if (t < BUCKET_SIZE) lcnt[t] = 0;
    __syncthreads();
    // per-node histogram
    for (int r = t; r < cb; r += 256)
        atomicAdd(&lcnt[lrec[r] & 127u], 1);
    __syncthreads();
    int v = 0, pcnt = 0;
    if (t < BUCKET_SIZE) {
        v = lcnt[t];
        pcnt = (v + 7) & ~7;     // pad to multiple of 8
        sc[t] = pcnt;
    }
    __syncthreads();
    for (int off = 1; off < BUCKET_SIZE; off <<= 1) {
        int xx = 0;
        if (t < BUCKET_SIZE) {
            xx = sc[t];
            if (t >= off) xx += sc[t - off];
        }
        __syncthreads();
        if (t < BUCKET_SIZE) sc[t] = xx;
        __syncthreads();
    }
    if (t < BUCKET_SIZE) {
        int start = b * CAP + sc[t] - pcnt;   // exclusive scan of padded counts
        if (n0 + t < n) re[n0 + t] = make_int2(start, start + v);
        cur[t] = start;
        for (int z = start + v; z < start + pcnt; z++) soff[z] = ZOFF;
    }
    __syncthreads();
    for (int r = t; r < cb; r += 256) {
        unsigned rec = lrec[r];
        int p = atomicAdd(&cur[rec & 127u], 1);
        soff[p] = rec & ~127u;   // src * 128 byte offset
    }
}

// ---------------- aggregation: aggb[i] = sum_{j->i} h[j] (bf16 in/out) -----
// one wave per node; 8 edges per VMEM instruction: lane = q*8+sl,
// q = edge slot (0..7), sl = 16B feature slice (0..7, uint4 load).
// Edge lists 8-padded with zero-row offsets -> NO tail bounds logic.

__global__ __launch_bounds__(256) void k_agg(
    const unsigned short* __restrict__ hb, unsigned short* __restrict__ aggb,
    const int2* __restrict__ re, const unsigned int* __restrict__ soff, int n) {
    int lane = threadIdx.x & 63;
    int i = (blockIdx.x * 256 + threadIdx.x) >> 6;
    if (i >= n) return;
    int q = lane >> 3;
    int sl = lane & 7;
    int2 bounds = re[i];
    int e0 = bounds.x, e1 = bounds.y;
    int iters = (e1 - e0 + 7) >> 3;
    const char* base = (const char*)hb + sl * 16;

    vf2 A[4], B[4];
#pragma unroll
    for (int f = 0; f < 4; f++) { A[f] = (vf2){0.f, 0.f}; B[f] = (vf2){0.f, 0.f}; }

    int eq = e0 + q;
    int it = 0;
    for (; it + 2 <= iters; it += 2) {
        int ea = eq + it * 8, eb = ea + 8;
        unsigned oa = __builtin_nontemporal_load(soff + ea);
        unsigned ob = __builtin_nontemporal_load(soff + eb);
        uint4 da = *(const uint4*)(base + oa);
        uint4 db = *(const uint4*)(base + ob);
        A[0] += bpair(da.x); A[1] += bpair(da.y);
        A[2] += bpair(da.z); A[3] += bpair(da.w);
        B[0] += bpair(db.x); B[1] += bpair(db.y);
        B[2] += bpair(db.z); B[3] += bpair(db.w);
    }
    if (it < iters) {
        int ea = eq + it * 8;
        unsigned oa = __builtin_nontemporal_load(soff + ea);
        uint4 da = *(const uint4*)(base + oa);
        A[0] += bpair(da.x); A[1] += bpair(da.y);
        A[2] += bpair(da.z); A[3] += bpair(da.w);
    }

    float f[8];
#pragma unroll
    for (int k = 0; k < 4; k++) {
        vf2 s2 = A[k] + B[k];
        float slo = s2.x, shi = s2.y;
        slo += __shfl_xor(slo, 8);
        slo += __shfl_xor(slo, 16);
        slo += __shfl_xor(slo, 32);
        shi += __shfl_xor(shi, 8);
        shi += __shfl_xor(shi, 16);
        shi += __shfl_xor(shi, 32);
        f[2 * k] = slo;
        f[2 * k + 1] = shi;
    }
    if (q == 0) {
        uint4 o;
        o.x = pk2(f[0], f[1]);
        o.y = pk2(f[2], f[3]);
        o.z = pk2(f[4], f[5]);
        o.w = pk2(f[6], f[7]);
        *(uint4*)((char*)aggb + (size_t)i * 128 + sl * 16) = o;
    }
}

// ---------------- MFMA gemm: hbout = [relu]([hb|aggb] @ Wt^T + brel) -------

template <int RELU>
__global__ __launch_bounds__(256) void k_gemm(
    const unsigned short* __restrict__ hb, const unsigned short* __restrict__ aggb,
    const unsigned short* __restrict__ wt, const float* __restrict__ brel,
    unsigned short* __restrict__ hbout, int n) {
    __shared__ float sc[4][16 * 68];

    int tid = threadIdx.x;
    int w = tid >> 6, l = tid & 63;
    int lm = l & 15, q = l >> 4;
    int r0 = blockIdx.x * 64 + w * 16;

    int arow = r0 + lm;
    if (arow >= n) arow = n - 1;
    const unsigned short* ah = hb + (size_t)arow * 64 + q * 8;
    const unsigned short* aa = aggb + (size_t)arow * 64 + q * 8;
    vbf8 afr[4];
    afr[0] = *(const vbf8*)(ah);
    afr[1] = *(const vbf8*)(ah + 32);
    afr[2] = *(const vbf8*)(aa);
    afr[3] = *(const vbf8*)(aa + 32);

    vf4 acc[4];
#pragma unroll
    for (int t = 0; t < 4; t++) acc[t] = (vf4){0.f, 0.f, 0.f, 0.f};

#pragma unroll
    for (int t = 0; t < 4; t++) {
        const unsigned short* wrow = wt + (size_t)(t * 16 + lm) * 128 + q * 8;
#pragma unroll
        for (int s = 0; s < 4; s++) {
            vbf8 bfr = *(const vbf8*)(wrow + s * 32);
            acc[t] = __builtin_amdgcn_mfma_f32_16x16x32_bf16(afr[s], bfr, acc[t], 0, 0, 0);
        }
    }

    float* sw_ = sc[w];
#pragma unroll
    for (int t = 0; t < 4; t++) {
        float b = brel[t * 16 + lm];
#pragma unroll
        for (int i = 0; i < 4; i++) {
            float v = acc[t][i] + b;
            if (RELU) v = fmaxf(v, 0.f);
            sw_[(q * 4 + i) * 68 + t * 16 + lm] = v;
        }
    }
    int rr = l >> 2, cs = l & 3;
    int node = r0 + rr;
    if (node < n) {
        const float* rp = sw_ + rr * 68 + cs * 16;
        float4 v0 = *(const float4*)(rp);
        float4 v1 = *(const float4*)(rp + 4);
        float4 v2 = *(const float4*)(rp + 8);
        float4 v3 = *(const float4*)(rp + 12);
        uint4 o0, o1;
        o0.x = pk2(v0.x, v0.y);
        o0.y = pk2(v0.z, v0.w);
        o0.z = pk2(v1.x, v1.y);
        o0.w = pk2(v1.z, v1.w);
        o1.x = pk2(v2.x, v2.y);
        o1.y = pk2(v2.z, v2.w);
        o1.z = pk2(v3.x, v3.y);
        o1.w = pk2(v3.z, v3.w);
        uint4* op = (uint4*)(hbout + (size_t)node * 64 + cs * 16);
        op[0] = o0;
        op[1] = o1;
    }
}

// ---------------- fused pool + MLP head (one block per graph) --------------

__global__ __launch_bounds__(256) void k_poolmlp(
    const unsigned short* __restrict__ hb, const int* __restrict__ batch,
    const float* __restrict__ T, const float* __restrict__ w1,
    const float* __restrict__ b1, const float* __restrict__ w2,
    const float* __restrict__ b2, const float* __restrict__ w3,
    const float* __restrict__ b3, float* __restrict__ out, int n) {
    __shared__ float psum[4][64];
    __shared__ float pmax[4][64];
    __shared__ float sin_[200];
    __shared__ float so1[256];
    __shared__ float red[256];
    int g = blockIdx.x, t = threadIdx.x;
    int l = t & 63, c = t >> 6;

    // bounds via binary search (batch sorted)
    int lo = 0, hi = n;
    while (lo < hi) { int m = (lo + hi) >> 1; if (batch[m] < g) lo = m + 1; else hi = m; }
    int s0 = lo;
    int lo2 = s0, hi2 = n;
    while (lo2 < hi2) { int m = (lo2 + hi2) >> 1; if (batch[m] < g + 1) lo2 = m + 1; else hi2 = m; }
    int s1 = lo2;

    // pooling: unroll x4 (independent loads in flight)
    float sa0 = 0.f, sa1 = 0.f, sa2 = 0.f, sa3 = 0.f;
    float ma0 = -INFINITY, ma1 = -INFINITY, ma2 = -INFINITY, ma3 = -INFINITY;
    int nn = s0 + c;
    for (; nn + 12 < s1; nn += 16) {
        float v0 = b2f(hb[(size_t)nn * 64 + l]);
        float v1 = b2f(hb[(size_t)(nn + 4) * 64 + l]);
        float v2 = b2f(hb[(size_t)(nn + 8) * 64 + l]);
        float v3 = b2f(hb[(size_t)(nn + 12) * 64 + l]);
        sa0 += v0; sa1 += v1; sa2 += v2; sa3 += v3;
        ma0 = fmaxf(ma0, v0); ma1 = fmaxf(ma1, v1);
        ma2 = fmaxf(ma2, v2); ma3 = fmaxf(ma3, v3);
    }
    for (; nn < s1; nn += 4) {
        float v = b2f(hb[(size_t)nn * 64 + l]);
        sa0 += v;
        ma0 = fmaxf(ma0, v);
    }
    psum[c][l] = (sa0 + sa1) + (sa2 + sa3);
    pmax[c][l] = fmaxf(fmaxf(ma0, ma1), fmaxf(ma2, ma3));
    __syncthreads();
    if (t < 64) {
        float s = (psum[0][t] + psum[1][t]) + (psum[2][t] + psum[3][t]);
        float mx = fmaxf(fmaxf(pmax[0][t], pmax[1][t]), fmaxf(pmax[2][t], pmax[3][t]));
        int cnt = s1 - s0;
        float mean = s / fmaxf((float)cnt, 1.f);
        if (cnt == 0) mx = 0.f;
        sin_[t] = mx;
        sin_[64 + t] = mean;
        sin_[128 + t] = s;
        if (t == 0) {
            sin_[192] = T[g];
#pragma unroll
            for (int z = 193; z < 200; z++) sin_[z] = 0.f;  // pad for x8 batch
        }
    }
    __syncthreads();

    // layer 1: 193-K matvec, batched x8 (pad zeros make 200 safe)
    float a = b1[t];
    {
        float wv[8];
        for (int k = 0; k < 192; k += 8) {
#pragma unroll
            for (int u = 0; u < 8; u++) wv[u] = w1[(k + u) * 256 + t];
#pragma unroll
            for (int u = 0; u < 8; u++) a += sin_[k + u] * wv[u];
        }
        a += sin_[192] * w1[192 * 256 + t];
    }
    a = fmaxf(a, 0.f);
    so1[t] = a;
    __syncthreads();

    // layer 2: 256-K matvec, batched x8
    float a2 = b2[t];
    {
        float wv[8];
        for (int k = 0; k < 256; k += 8) {
#pragma unroll
            for (int u = 0; u < 8; u++) wv[u] = w2[(k + u) * 256 + t];
#pragma unroll
            for (int u = 0; u < 8; u++) a2 += so1[k + u] * wv[u];
        }
    }
    a2 = fmaxf(a2, 0.f);
    red[t] = a2 * w3[t];
    __syncthreads();
    for (int s = 128; s > 0; s >>= 1) {
        if (t < s) red[t] += red[t + s];
        __syncthreads();
    }
    if (t == 0) out[g] = red[0] + b3[0];
}

extern "C" void kernel_launch(void* const* d_in, const int* in_sizes, int n_in,
                              void* d_out, int out_size, void* d_ws, size_t ws_size,
                              hipStream_t stream) {
    const int N = N_NODES, E = N_EDGES, G = N_GRAPHS;

    const float* x = (const float*)d_in[0];
    const int* ei = (const int*)d_in[1];
    const int* batch = (const int*)d_in[2];
    const float* T = (const float*)d_in[3];
    const float* wrel[4] = {(const float*)d_in[4], (const float*)d_in[7],
                            (const float*)d_in[10], (const float*)d_in[13]};
    const float* brel[4] = {(const float*)d_in[5], (const float*)d_in[8],
                            (const float*)d_in[11], (const float*)d_in[14]};
    const float* wroot[4] = {(const float*)d_in[6], (const float*)d_in[9],
                             (const float*)d_in[12], (const float*)d_in[15]};
    const float* w1 = (const float*)d_in[16];
    const float* b1 = (const float*)d_in[17];
    const float* w2 = (const float*)d_in[18];
    const float* b2 = (const float*)d_in[19];
    const float* w3 = (const float*)d_in[20];
    const float* b3 = (const float*)d_in[21];
    float* out = (float*)d_out;

    const int* esrc = ei;
    const int* edst = ei + E;

    // workspace layout (~60 MB)
    char* ws = (char*)d_ws;
    size_t off = 0;
    auto alloc = [&](size_t bytes) {
        size_t r = off;
        off = (off + bytes + 255) & ~(size_t)255;
        return r;
    };
    int* lofs = (int*)(ws + alloc((size_t)SCAT_BLOCKS * LOFS_W * 4));
    int2* re = (int2*)(ws + alloc((size_t)N * 8));
    unsigned int* soff = (unsigned int*)(ws + alloc((size_t)NB * CAP * 4));
    unsigned int* ebuf = (unsigned int*)(ws + alloc((size_t)SCAT_BLOCKS * EDGES_PER_BLOCK * 4));
    unsigned short* hbA = (unsigned short*)(ws + alloc((size_t)N * 64 * 2 + 128));
    unsigned short* hbB = (unsigned short*)(ws + alloc((size_t)N * 64 * 2 + 128));
    unsigned short* aggb = (unsigned short*)(ws + alloc((size_t)N * 64 * 2));
    unsigned short* wt = (unsigned short*)(ws + alloc((size_t)4 * 64 * 128 * 2));

    // 1. prep: mega (LDS bucket-sort scatter + f2b + wprep), then fscatter2
    k_mega<<<SCAT_BLOCKS + F2B_BLOCKS + WPREP_BLOCKS, 256, 0, stream>>>(
        esrc, edst, lofs, ebuf, (const float4*)x, (uint2*)hbA,
        wroot[0], wrel[0], wroot[1], wrel[1],
        wroot[2], wrel[2], wroot[3], wrel[3], wt);
    k_fscatter2<<<NB, 256, 0, stream>>>(ebuf, lofs, re, soff, hbA, hbB, N);

    // 2. four conv layers (bf16 h ping-pong, MFMA gemm)
    int agg_blocks = (N * 64 + 255) / 256;   // one wave per node
    int gemm_blocks = (N + 63) / 64;         // 64-node tile per block

    k_agg<<<agg_blocks, 256, 0, stream>>>(hbA, aggb, re, soff, N);
    k_gemm<1><<<gemm_blocks, 256, 0, stream>>>(hbA, aggb, wt + 0 * 8192, brel[0], hbB, N);

    k_agg<<<agg_blocks, 256, 0, stream>>>(hbB, aggb, re, soff, N);
    k_gemm<1><<<gemm_blocks, 256, 0, stream>>>(hbB, aggb, wt + 1 * 8192, brel[1], hbA, N);

    k_agg<<<agg_blocks, 256, 0, stream>>>(hbA, aggb, re, soff, N);
    k_gemm<1><<<gemm_blocks, 256, 0, stream>>>(hbA, aggb, wt + 2 * 8192, brel[2], hbB, N);

    k_agg<<<agg_blocks, 256, 0, stream>>>(hbB, aggb, re, soff, N);
    k_gemm<0><<<gemm_blocks, 256, 0, stream>>>(hbB, aggb, wt + 3 * 8192, brel[3], hbA, N);

    // 3. fused pooling + MLP head
    k_poolmlp<<<G, 256, 0, stream>>>(hbA, batch, T, w1, b1, w2, b2, w3, b3, out, N);
}